// Round 1
// baseline (728.106 us; speedup 1.0000x reference)
//
#include <hip/hip_runtime.h>

typedef unsigned short u16;
using bf16x8 = __attribute__((ext_vector_type(8))) __bf16;
using f32x4  = __attribute__((ext_vector_type(4))) float;

#define BATCH 8
#define CH    256
#define NPIX  16384
#define GN_EPS   1e-5f
#define ATTN_EPS 1e-6f

__device__ __forceinline__ u16 f2bf(float f) {
  unsigned int u = __float_as_uint(f);
  u += 0x7fffu + ((u >> 16) & 1u);
  return (u16)(u >> 16);
}

// ---------------- weight convert: fp32 -> bf16 ----------------
__global__ void conv_w_kernel(const float* __restrict__ Wq, const float* __restrict__ Wk,
                              const float* __restrict__ Wv,
                              u16* __restrict__ oq, u16* __restrict__ ok, u16* __restrict__ ov) {
  int i = blockIdx.x * 256 + threadIdx.x;  // 65536 total
  oq[i] = f2bf(Wq[i]);
  ok[i] = f2bf(Wk[i]);
  ov[i] = f2bf(Wv[i]);
}

// ---------------- GroupNorm stats: per (b,g) sum / sumsq ----------------
__global__ void stats_kernel(const float* __restrict__ x, float* __restrict__ sum,
                             float* __restrict__ sqs) {
  const int gi = blockIdx.x >> 3;   // 0..63  (b*8+g)
  const int sp = blockIdx.x & 7;    // split
  const float4* p = (const float4*)x + (size_t)gi * 131072 + (size_t)sp * 16384;
  float s = 0.f, ss = 0.f;
  for (int i = 0; i < 64; ++i) {
    float4 v = p[threadIdx.x + i * 256];
    s  += v.x + v.y + v.z + v.w;
    ss += v.x * v.x + v.y * v.y + v.z * v.z + v.w * v.w;
  }
  for (int off = 32; off; off >>= 1) {
    s  += __shfl_xor(s, off);
    ss += __shfl_xor(ss, off);
  }
  __shared__ float rs[4], rss[4];
  const int wave = threadIdx.x >> 6, lane = threadIdx.x & 63;
  if (!lane) { rs[wave] = s; rss[wave] = ss; }
  __syncthreads();
  if (!threadIdx.x) {
    atomicAdd(&sum[gi], rs[0] + rs[1] + rs[2] + rs[3]);
    atomicAdd(&sqs[gi], rss[0] + rss[1] + rss[2] + rss[3]);
  }
}

// ---------------- fold stats+gamma/beta into per-(b,c) scale/shift ----------------
__global__ void finalize_kernel(const float* __restrict__ sums, const float* __restrict__ sqs,
                                const float* __restrict__ gamma, const float* __restrict__ beta,
                                float* __restrict__ sA, float* __restrict__ sB) {
  const int t = blockIdx.x * 256 + threadIdx.x;  // 0..2047
  const int c = t & 255;
  const int gi = (t >> 8) * 8 + (c >> 5);
  const float inv = 1.f / 524288.f;
  const float mean = sums[gi] * inv;
  const float var = sqs[gi] * inv - mean * mean;
  const float rstd = rsqrtf(var + GN_EPS);
  const float a = rstd * gamma[c];
  sA[t] = a;
  sB[t] = beta[c] - mean * a;
}

// ---------------- fused: xn -> K,V convs -> KV += K*V^T, ksum ----------------
// grid 256: b = bid>>5, split = bid&31 (512 pixels each, 8 chunks of 64)
__global__ __launch_bounds__(1024, 4) void fused_kv_kernel(
    const float* __restrict__ x, const u16* __restrict__ Wkb, const u16* __restrict__ Wvb,
    const float* __restrict__ bk, const float* __restrict__ bv,
    const float* __restrict__ sA, const float* __restrict__ sB,
    float* __restrict__ ksum, float* __restrict__ KV) {
  // xnv: xn pixel-major [64][288]; later in each chunk reused as Vcp [256][72]
  __shared__ __align__(16) u16 xnv[64 * 288];
  __shared__ __align__(16) u16 Kcp[256 * 72];

  const int b = blockIdx.x >> 5;
  const int sp = blockIdx.x & 31;
  const int tid = threadIdx.x;
  const int wave = tid >> 6;
  const int lane = tid & 63;
  const int m = lane & 15;
  const int q = lane >> 4;

  const int ctg = wave & 7;   // G1: pair of c_out tiles {2ctg, 2ctg+1}
  const int ptg = wave >> 3;  // G1: pair of pixel tiles {2ptg, 2ptg+1}
  const int ckg = wave >> 2;  // G2: c_k tiles [4ckg..+3]
  const int cvg = wave & 3;   // G2: c_v tiles [4cvg..+3]

  const float* xb = x + (size_t)b * CH * NPIX;
  const float* sAb = sA + b * CH;
  const float* sBb = sB + b * CH;

  f32x4 accKV[4][4];
#pragma unroll
  for (int i = 0; i < 4; ++i)
#pragma unroll
    for (int j = 0; j < 4; ++j) accKV[i][j] = {0.f, 0.f, 0.f, 0.f};
  float ksum_acc = 0.f;

  const int p_ = tid & 63;
  const int cq = tid >> 6;  // 0..15

  for (int ch = 0; ch < 8; ++ch) {
    const int pix0 = sp * 512 + ch * 64;
    __syncthreads();  // xnv (incl. Vcp alias) free to overwrite
    // ---- stage xn: normalize -> bf16, pixel-major [p][c], stride 288 ----
#pragma unroll
    for (int i = 0; i < 4; ++i) {
      const int c = (cq + 16 * i) * 4;
      const float v0 = xb[(size_t)(c + 0) * NPIX + pix0 + p_] * sAb[c + 0] + sBb[c + 0];
      const float v1 = xb[(size_t)(c + 1) * NPIX + pix0 + p_] * sAb[c + 1] + sBb[c + 1];
      const float v2 = xb[(size_t)(c + 2) * NPIX + pix0 + p_] * sAb[c + 2] + sBb[c + 2];
      const float v3 = xb[(size_t)(c + 3) * NPIX + pix0 + p_] * sAb[c + 3] + sBb[c + 3];
      const unsigned int lo = (unsigned int)f2bf(v0) | ((unsigned int)f2bf(v1) << 16);
      const unsigned int hi = (unsigned int)f2bf(v2) | ((unsigned int)f2bf(v3) << 16);
      *(uint2*)&xnv[p_ * 288 + c] = make_uint2(lo, hi);
    }
    __syncthreads();

    // ---- G1-K: K = elu(Wk . xn + bk)+1 -> Kcp c-major [256][72] ----
    f32x4 ac[2][2];
#pragma unroll
    for (int i = 0; i < 2; ++i)
#pragma unroll
      for (int pp = 0; pp < 2; ++pp) ac[i][pp] = {0.f, 0.f, 0.f, 0.f};
#pragma unroll
    for (int ks = 0; ks < 8; ++ks) {
      const bf16x8 a0 = *(const bf16x8*)(Wkb + ((2 * ctg + 0) * 16 + m) * 256 + ks * 32 + q * 8);
      const bf16x8 a1 = *(const bf16x8*)(Wkb + ((2 * ctg + 1) * 16 + m) * 256 + ks * 32 + q * 8);
#pragma unroll
      for (int pp = 0; pp < 2; ++pp) {
        const bf16x8 bfr = *(const bf16x8*)&xnv[((2 * ptg + pp) * 16 + m) * 288 + ks * 32 + q * 8];
        ac[0][pp] = __builtin_amdgcn_mfma_f32_16x16x32_bf16(a0, bfr, ac[0][pp], 0, 0, 0);
        ac[1][pp] = __builtin_amdgcn_mfma_f32_16x16x32_bf16(a1, bfr, ac[1][pp], 0, 0, 0);
      }
    }
#pragma unroll
    for (int i = 0; i < 2; ++i) {
#pragma unroll
      for (int r = 0; r < 4; ++r) {
        const int row = (2 * ctg + i) * 16 + q * 4 + r;
        const float bias = bk[row];
#pragma unroll
        for (int pp = 0; pp < 2; ++pp) {
          float v = ac[i][pp][r] + bias;
          v = v > 0.f ? v + 1.f : __expf(v);
          Kcp[row * 72 + (2 * ptg + pp) * 16 + m] = f2bf(v);
        }
      }
    }

    // ---- G1-V: V = Wv . xn + bv (compute in regs; store after barrier into xnv space) ----
    f32x4 av[2][2];
#pragma unroll
    for (int i = 0; i < 2; ++i)
#pragma unroll
      for (int pp = 0; pp < 2; ++pp) av[i][pp] = {0.f, 0.f, 0.f, 0.f};
#pragma unroll
    for (int ks = 0; ks < 8; ++ks) {
      const bf16x8 a0 = *(const bf16x8*)(Wvb + ((2 * ctg + 0) * 16 + m) * 256 + ks * 32 + q * 8);
      const bf16x8 a1 = *(const bf16x8*)(Wvb + ((2 * ctg + 1) * 16 + m) * 256 + ks * 32 + q * 8);
#pragma unroll
      for (int pp = 0; pp < 2; ++pp) {
        const bf16x8 bfr = *(const bf16x8*)&xnv[((2 * ptg + pp) * 16 + m) * 288 + ks * 32 + q * 8];
        av[0][pp] = __builtin_amdgcn_mfma_f32_16x16x32_bf16(a0, bfr, av[0][pp], 0, 0, 0);
        av[1][pp] = __builtin_amdgcn_mfma_f32_16x16x32_bf16(a1, bfr, av[1][pp], 0, 0, 0);
      }
    }
    __syncthreads();  // all xn reads done; safe to overwrite xnv with Vcp
    u16* Vcp = xnv;   // [256][72]
#pragma unroll
    for (int i = 0; i < 2; ++i) {
#pragma unroll
      for (int r = 0; r < 4; ++r) {
        const int row = (2 * ctg + i) * 16 + q * 4 + r;
        const float bias = bv[row];
#pragma unroll
        for (int pp = 0; pp < 2; ++pp)
          Vcp[row * 72 + (2 * ptg + pp) * 16 + m] = f2bf(av[i][pp][r] + bias);
      }
    }
    __syncthreads();  // Kcp + Vcp complete

    // ---- ksum partial (from activated K in LDS) ----
    {
      const int krow = tid & 255;
      const int kseg = tid >> 8;  // 0..3 -> cols kseg*16..+15
      const bf16x8 k0 = *(const bf16x8*)&Kcp[krow * 72 + kseg * 16];
      const bf16x8 k1 = *(const bf16x8*)&Kcp[krow * 72 + kseg * 16 + 8];
      float s = 0.f;
#pragma unroll
      for (int j = 0; j < 8; ++j) s += (float)k0[j] + (float)k1[j];
      ksum_acc += s;
    }

    // ---- G2: KV += K . V^T ----
#pragma unroll
    for (int ks = 0; ks < 2; ++ks) {
      bf16x8 af[4], bfv[4];
#pragma unroll
      for (int i = 0; i < 4; ++i)
        af[i] = *(const bf16x8*)&Kcp[((4 * ckg + i) * 16 + m) * 72 + ks * 32 + q * 8];
#pragma unroll
      for (int j = 0; j < 4; ++j)
        bfv[j] = *(const bf16x8*)&Vcp[((4 * cvg + j) * 16 + m) * 72 + ks * 32 + q * 8];
#pragma unroll
      for (int i = 0; i < 4; ++i)
#pragma unroll
        for (int j = 0; j < 4; ++j)
          accKV[i][j] = __builtin_amdgcn_mfma_f32_16x16x32_bf16(af[i], bfv[j], accKV[i][j], 0, 0, 0);
    }
  }

  // ---- block epilogue: atomics ----
  atomicAdd(&ksum[b * CH + (tid & 255)], ksum_acc);
  float* KVb = KV + (size_t)b * CH * CH;
#pragma unroll
  for (int i = 0; i < 4; ++i)
#pragma unroll
    for (int j = 0; j < 4; ++j)
#pragma unroll
      for (int r = 0; r < 4; ++r) {
        const int row = (4 * ckg + i) * 16 + q * 4 + r;
        const int col = (4 * cvg + j) * 16 + m;
        atomicAdd(&KVb[row * CH + col], accKV[i][j][r]);
      }
}

// ---------------- M[b] = Wp . (KV / (ksum+eps)) -> bf16 ----------------
__global__ __launch_bounds__(256) void m_kernel(const float* __restrict__ Wp,
                                                const float* __restrict__ KV,
                                                const float* __restrict__ ksum,
                                                u16* __restrict__ Mb) {
  __shared__ float WpL[16 * 256];
  const int b = blockIdx.x >> 4;
  const int rt = blockIdx.x & 15;
  const int tid = threadIdx.x;
#pragma unroll
  for (int i = 0; i < 16; ++i) WpL[i * 256 + tid] = Wp[(rt * 16 + i) * 256 + tid];
  __syncthreads();
  float acc[16];
#pragma unroll
  for (int r = 0; r < 16; ++r) acc[r] = 0.f;
  const float* KVb = KV + (size_t)b * 65536;
  const float* ksb = ksum + b * 256;
  for (int k = 0; k < 256; ++k) {
    const float rs = 1.f / (ksb[k] + ATTN_EPS);
    const float v = KVb[k * 256 + tid] * rs;
#pragma unroll
    for (int r = 0; r < 16; ++r) acc[r] += WpL[r * 256 + k] * v;
  }
#pragma unroll
  for (int r = 0; r < 16; ++r) Mb[(size_t)b * 65536 + (rt * 16 + r) * 256 + tid] = f2bf(acc[r]);
}

// ---------------- out = M . (elu(Wq.xn+bq)+1) + bp + x ----------------
// grid 2048: b = bid>>8, 64-pixel chunk = bid&255
__global__ __launch_bounds__(256, 4) void out_kernel(
    const float* __restrict__ x, const u16* __restrict__ Wqb, const float* __restrict__ bq,
    const float* __restrict__ sA, const float* __restrict__ sB, const u16* __restrict__ Mb,
    const float* __restrict__ bp, float* __restrict__ out) {
  __shared__ __align__(16) u16 xn2[64 * 288];  // xn pixel-major
  __shared__ __align__(16) u16 qpc[64 * 288];  // q pixel-major
  const int b = blockIdx.x >> 8;
  const int pix0 = (blockIdx.x & 255) * 64;
  const int tid = threadIdx.x;
  const int wave = tid >> 6;  // 0..3
  const int lane = tid & 63;
  const int m = lane & 15;
  const int q = lane >> 4;

  const float* xb = x + (size_t)b * CH * NPIX;
  const float* sAb = sA + b * CH;
  const float* sBb = sB + b * CH;

  const int p_ = tid & 63;
  const int cq = tid >> 6;  // 0..3
#pragma unroll
  for (int i = 0; i < 16; ++i) {
    const int c = (cq + 4 * i) * 4;
    const float v0 = xb[(size_t)(c + 0) * NPIX + pix0 + p_] * sAb[c + 0] + sBb[c + 0];
    const float v1 = xb[(size_t)(c + 1) * NPIX + pix0 + p_] * sAb[c + 1] + sBb[c + 1];
    const float v2 = xb[(size_t)(c + 2) * NPIX + pix0 + p_] * sAb[c + 2] + sBb[c + 2];
    const float v3 = xb[(size_t)(c + 3) * NPIX + pix0 + p_] * sAb[c + 3] + sBb[c + 3];
    const unsigned int lo = (unsigned int)f2bf(v0) | ((unsigned int)f2bf(v1) << 16);
    const unsigned int hi = (unsigned int)f2bf(v2) | ((unsigned int)f2bf(v3) << 16);
    *(uint2*)&xn2[p_ * 288 + c] = make_uint2(lo, hi);
  }
  __syncthreads();

  // G3: q^T = xn^T . Wq^T  (D rows = pixels, cols = c2)
  f32x4 aq[4][4];  // [pt][ct]
#pragma unroll
  for (int pt = 0; pt < 4; ++pt)
#pragma unroll
    for (int ct = 0; ct < 4; ++ct) aq[pt][ct] = {0.f, 0.f, 0.f, 0.f};
#pragma unroll
  for (int ks = 0; ks < 8; ++ks) {
    bf16x8 af[4];
#pragma unroll
    for (int pt = 0; pt < 4; ++pt)
      af[pt] = *(const bf16x8*)&xn2[(pt * 16 + m) * 288 + ks * 32 + q * 8];
#pragma unroll
    for (int ct = 0; ct < 4; ++ct) {
      const bf16x8 bfr = *(const bf16x8*)(Wqb + ((4 * wave + ct) * 16 + m) * 256 + ks * 32 + q * 8);
#pragma unroll
      for (int pt = 0; pt < 4; ++pt)
        aq[pt][ct] = __builtin_amdgcn_mfma_f32_16x16x32_bf16(af[pt], bfr, aq[pt][ct], 0, 0, 0);
    }
  }
#pragma unroll
  for (int ct = 0; ct < 4; ++ct) {
    const int c2 = (4 * wave + ct) * 16 + m;
    const float bias = bq[c2];
#pragma unroll
    for (int pt = 0; pt < 4; ++pt)
#pragma unroll
      for (int r = 0; r < 4; ++r) {
        float v = aq[pt][ct][r] + bias;
        v = v > 0.f ? v + 1.f : __expf(v);
        qpc[(pt * 16 + q * 4 + r) * 288 + c2] = f2bf(v);
      }
  }
  __syncthreads();

  // G4: out = M . q
  f32x4 ao[4][4];  // [ct][pt]
#pragma unroll
  for (int ct = 0; ct < 4; ++ct)
#pragma unroll
    for (int pt = 0; pt < 4; ++pt) ao[ct][pt] = {0.f, 0.f, 0.f, 0.f};
  const u16* Ab = Mb + (size_t)b * 65536;
#pragma unroll
  for (int ks = 0; ks < 8; ++ks) {
    bf16x8 af2[4];
#pragma unroll
    for (int ct = 0; ct < 4; ++ct)
      af2[ct] = *(const bf16x8*)(Ab + ((4 * wave + ct) * 16 + m) * 256 + ks * 32 + q * 8);
#pragma unroll
    for (int pt = 0; pt < 4; ++pt) {
      const bf16x8 bfr = *(const bf16x8*)&qpc[(pt * 16 + m) * 288 + ks * 32 + q * 8];
#pragma unroll
      for (int ct = 0; ct < 4; ++ct)
        ao[ct][pt] = __builtin_amdgcn_mfma_f32_16x16x32_bf16(af2[ct], bfr, ao[ct][pt], 0, 0, 0);
    }
  }
  float* ob = out + (size_t)b * CH * NPIX;
#pragma unroll
  for (int ct = 0; ct < 4; ++ct)
#pragma unroll
    for (int r = 0; r < 4; ++r) {
      const int row = (4 * wave + ct) * 16 + q * 4 + r;
      const float bias = bp[row];
#pragma unroll
      for (int pt = 0; pt < 4; ++pt) {
        const int idx = row * NPIX + pix0 + pt * 16 + m;
        ob[idx] = ao[ct][pt][r] + bias + xb[idx];
      }
    }
}

// ---------------- launch ----------------
extern "C" void kernel_launch(void* const* d_in, const int* in_sizes, int n_in,
                              void* d_out, int out_size, void* d_ws, size_t ws_size,
                              hipStream_t stream) {
  const float* x     = (const float*)d_in[0];
  const float* gamma = (const float*)d_in[1];
  const float* beta  = (const float*)d_in[2];
  const float* Wq    = (const float*)d_in[3];
  const float* bq    = (const float*)d_in[4];
  const float* Wk    = (const float*)d_in[5];
  const float* bk    = (const float*)d_in[6];
  const float* Wv    = (const float*)d_in[7];
  const float* bv    = (const float*)d_in[8];
  const float* Wp    = (const float*)d_in[9];
  const float* bp    = (const float*)d_in[10];
  float* out = (float*)d_out;

  float* wsf  = (float*)d_ws;
  float* sum  = wsf;              // 64
  float* sqs  = wsf + 64;         // 64
  float* ksum = wsf + 128;        // 2048
  float* KV   = wsf + 2176;       // 524288
  float* sA   = wsf + 526464;     // 2048
  float* sB   = wsf + 528512;     // 2048
  u16* Wqb = (u16*)(wsf + 530560);  // 65536
  u16* Wkb = Wqb + 65536;
  u16* Wvb = Wkb + 65536;
  u16* Mb  = Wvb + 65536;           // 524288

  hipMemsetAsync(wsf, 0, (size_t)526464 * sizeof(float), stream);
  conv_w_kernel<<<256, 256, 0, stream>>>(Wq, Wk, Wv, Wqb, Wkb, Wvb);
  stats_kernel<<<512, 256, 0, stream>>>(x, sum, sqs);
  finalize_kernel<<<8, 256, 0, stream>>>(sum, sqs, gamma, beta, sA, sB);
  fused_kv_kernel<<<256, 1024, 0, stream>>>(x, Wkb, Wvb, bk, bv, sA, sB, ksum, KV);
  m_kernel<<<128, 256, 0, stream>>>(Wp, KV, ksum, Mb);
  out_kernel<<<2048, 256, 0, stream>>>(x, Wqb, bq, sA, sB, Mb, bp, out);
}

// Round 3
// 726.842 us; speedup vs baseline: 1.0017x; 1.0017x over previous
//
#include <hip/hip_runtime.h>

typedef unsigned short u16;
using bf16x8 = __attribute__((ext_vector_type(8))) __bf16;
using f32x4  = __attribute__((ext_vector_type(4))) float;

#define BATCH 8
#define CH    256
#define NPIX  16384
#define GN_EPS   1e-5f
#define ATTN_EPS 1e-6f

__device__ __forceinline__ u16 f2bf(float f) {
  unsigned int u = __float_as_uint(f);
  u += 0x7fffu + ((u >> 16) & 1u);
  return (u16)(u >> 16);
}

// ---------------- weight convert: fp32 -> bf16 ----------------
__global__ void conv_w_kernel(const float* __restrict__ Wq, const float* __restrict__ Wk,
                              const float* __restrict__ Wv,
                              u16* __restrict__ oq, u16* __restrict__ ok, u16* __restrict__ ov) {
  int i = blockIdx.x * 256 + threadIdx.x;  // 65536 total
  oq[i] = f2bf(Wq[i]);
  ok[i] = f2bf(Wk[i]);
  ov[i] = f2bf(Wv[i]);
}

// ---------------- GroupNorm stats: per (b,g) sum / sumsq ----------------
__global__ void stats_kernel(const float* __restrict__ x, float* __restrict__ sum,
                             float* __restrict__ sqs) {
  const int gi = blockIdx.x >> 3;   // 0..63  (b*8+g)
  const int sp = blockIdx.x & 7;    // split
  const float4* p = (const float4*)x + (size_t)gi * 131072 + (size_t)sp * 16384;
  float s = 0.f, ss = 0.f;
  for (int i = 0; i < 64; ++i) {
    float4 v = p[threadIdx.x + i * 256];
    s  += v.x + v.y + v.z + v.w;
    ss += v.x * v.x + v.y * v.y + v.z * v.z + v.w * v.w;
  }
  for (int off = 32; off; off >>= 1) {
    s  += __shfl_xor(s, off);
    ss += __shfl_xor(ss, off);
  }
  __shared__ float rs[4], rss[4];
  const int wave = threadIdx.x >> 6, lane = threadIdx.x & 63;
  if (!lane) { rs[wave] = s; rss[wave] = ss; }
  __syncthreads();
  if (!threadIdx.x) {
    atomicAdd(&sum[gi], rs[0] + rs[1] + rs[2] + rs[3]);
    atomicAdd(&sqs[gi], rss[0] + rss[1] + rss[2] + rss[3]);
  }
}

// ---------------- fold stats+gamma/beta into per-(b,c) scale/shift ----------------
__global__ void finalize_kernel(const float* __restrict__ sums, const float* __restrict__ sqs,
                                const float* __restrict__ gamma, const float* __restrict__ beta,
                                float* __restrict__ sA, float* __restrict__ sB) {
  const int t = blockIdx.x * 256 + threadIdx.x;  // 0..2047
  const int c = t & 255;
  const int gi = (t >> 8) * 8 + (c >> 5);
  const float inv = 1.f / 524288.f;
  const float mean = sums[gi] * inv;
  const float var = sqs[gi] * inv - mean * mean;
  const float rstd = rsqrtf(var + GN_EPS);
  const float a = rstd * gamma[c];
  sA[t] = a;
  sB[t] = beta[c] - mean * a;
}

// ---------------- fused: xn -> K,V convs -> KV partial (or atomic), ksum ----------------
// grid 256: b = bid>>5, split = bid&31 (512 pixels each, 8 chunks of 64)
// mode 0: plain store of this block's partial to kvdst + bid*65536 (ws scratch)
// mode 1: atomicAdd into kvdst + b*65536 (fallback when ws is small)
__global__ __launch_bounds__(1024, 4) void fused_kv_kernel(
    const float* __restrict__ x, const u16* __restrict__ Wkb, const u16* __restrict__ Wvb,
    const float* __restrict__ bk, const float* __restrict__ bv,
    const float* __restrict__ sA, const float* __restrict__ sB,
    float* __restrict__ ksum, float* __restrict__ kvdst, int mode) {
  // xnv: xn pixel-major [64][288]; later in each chunk reused as Vcp [256][72]
  __shared__ __align__(16) u16 xnv[64 * 288];
  __shared__ __align__(16) u16 Kcp[256 * 72];

  const int b = blockIdx.x >> 5;
  const int sp = blockIdx.x & 31;
  const int tid = threadIdx.x;
  const int wave = tid >> 6;
  const int lane = tid & 63;
  const int m = lane & 15;
  const int q = lane >> 4;

  const int ctg = wave & 7;   // G1: pair of c_out tiles {2ctg, 2ctg+1}
  const int ptg = wave >> 3;  // G1: pair of pixel tiles {2ptg, 2ptg+1}
  const int ckg = wave >> 2;  // G2: c_k tiles [4ckg..+3]
  const int cvg = wave & 3;   // G2: c_v tiles [4cvg..+3]

  const float* xb = x + (size_t)b * CH * NPIX;
  const float* sAb = sA + b * CH;
  const float* sBb = sB + b * CH;

  f32x4 accKV[4][4];
#pragma unroll
  for (int i = 0; i < 4; ++i)
#pragma unroll
    for (int j = 0; j < 4; ++j) accKV[i][j] = {0.f, 0.f, 0.f, 0.f};
  float ksum_acc = 0.f;

  const int p_ = tid & 63;
  const int cq = tid >> 6;  // 0..15

  for (int ch = 0; ch < 8; ++ch) {
    const int pix0 = sp * 512 + ch * 64;
    __syncthreads();  // xnv (incl. Vcp alias) free to overwrite
    // ---- stage xn: normalize -> bf16, pixel-major [p][c], stride 288 ----
#pragma unroll
    for (int i = 0; i < 4; ++i) {
      const int c = (cq + 16 * i) * 4;
      const float v0 = xb[(size_t)(c + 0) * NPIX + pix0 + p_] * sAb[c + 0] + sBb[c + 0];
      const float v1 = xb[(size_t)(c + 1) * NPIX + pix0 + p_] * sAb[c + 1] + sBb[c + 1];
      const float v2 = xb[(size_t)(c + 2) * NPIX + pix0 + p_] * sAb[c + 2] + sBb[c + 2];
      const float v3 = xb[(size_t)(c + 3) * NPIX + pix0 + p_] * sAb[c + 3] + sBb[c + 3];
      const unsigned int lo = (unsigned int)f2bf(v0) | ((unsigned int)f2bf(v1) << 16);
      const unsigned int hi = (unsigned int)f2bf(v2) | ((unsigned int)f2bf(v3) << 16);
      *(uint2*)&xnv[p_ * 288 + c] = make_uint2(lo, hi);
    }
    __syncthreads();

    // ---- G1-K: K = elu(Wk . xn + bk)+1 -> Kcp c-major [256][72] ----
    f32x4 ac[2][2];
#pragma unroll
    for (int i = 0; i < 2; ++i)
#pragma unroll
      for (int pp = 0; pp < 2; ++pp) ac[i][pp] = {0.f, 0.f, 0.f, 0.f};
#pragma unroll
    for (int ks = 0; ks < 8; ++ks) {
      const bf16x8 a0 = *(const bf16x8*)(Wkb + ((2 * ctg + 0) * 16 + m) * 256 + ks * 32 + q * 8);
      const bf16x8 a1 = *(const bf16x8*)(Wkb + ((2 * ctg + 1) * 16 + m) * 256 + ks * 32 + q * 8);
#pragma unroll
      for (int pp = 0; pp < 2; ++pp) {
        const bf16x8 bfr = *(const bf16x8*)&xnv[((2 * ptg + pp) * 16 + m) * 288 + ks * 32 + q * 8];
        ac[0][pp] = __builtin_amdgcn_mfma_f32_16x16x32_bf16(a0, bfr, ac[0][pp], 0, 0, 0);
        ac[1][pp] = __builtin_amdgcn_mfma_f32_16x16x32_bf16(a1, bfr, ac[1][pp], 0, 0, 0);
      }
    }
#pragma unroll
    for (int i = 0; i < 2; ++i) {
#pragma unroll
      for (int r = 0; r < 4; ++r) {
        const int row = (2 * ctg + i) * 16 + q * 4 + r;
        const float bias = bk[row];
#pragma unroll
        for (int pp = 0; pp < 2; ++pp) {
          float v = ac[i][pp][r] + bias;
          v = v > 0.f ? v + 1.f : __expf(v);
          Kcp[row * 72 + (2 * ptg + pp) * 16 + m] = f2bf(v);
        }
      }
    }

    // ---- G1-V: V = Wv . xn + bv (compute in regs; store after barrier into xnv space) ----
    f32x4 av[2][2];
#pragma unroll
    for (int i = 0; i < 2; ++i)
#pragma unroll
      for (int pp = 0; pp < 2; ++pp) av[i][pp] = {0.f, 0.f, 0.f, 0.f};
#pragma unroll
    for (int ks = 0; ks < 8; ++ks) {
      const bf16x8 a0 = *(const bf16x8*)(Wvb + ((2 * ctg + 0) * 16 + m) * 256 + ks * 32 + q * 8);
      const bf16x8 a1 = *(const bf16x8*)(Wvb + ((2 * ctg + 1) * 16 + m) * 256 + ks * 32 + q * 8);
#pragma unroll
      for (int pp = 0; pp < 2; ++pp) {
        const bf16x8 bfr = *(const bf16x8*)&xnv[((2 * ptg + pp) * 16 + m) * 288 + ks * 32 + q * 8];
        av[0][pp] = __builtin_amdgcn_mfma_f32_16x16x32_bf16(a0, bfr, av[0][pp], 0, 0, 0);
        av[1][pp] = __builtin_amdgcn_mfma_f32_16x16x32_bf16(a1, bfr, av[1][pp], 0, 0, 0);
      }
    }
    __syncthreads();  // all xn reads done; safe to overwrite xnv with Vcp
    u16* Vcp = xnv;   // [256][72]
#pragma unroll
    for (int i = 0; i < 2; ++i) {
#pragma unroll
      for (int r = 0; r < 4; ++r) {
        const int row = (2 * ctg + i) * 16 + q * 4 + r;
        const float bias = bv[row];
#pragma unroll
        for (int pp = 0; pp < 2; ++pp)
          Vcp[row * 72 + (2 * ptg + pp) * 16 + m] = f2bf(av[i][pp][r] + bias);
      }
    }
    __syncthreads();  // Kcp + Vcp complete

    // ---- ksum partial (from activated K in LDS) ----
    {
      const int krow = tid & 255;
      const int kseg = tid >> 8;  // 0..3 -> cols kseg*16..+15
      const bf16x8 k0 = *(const bf16x8*)&Kcp[krow * 72 + kseg * 16];
      const bf16x8 k1 = *(const bf16x8*)&Kcp[krow * 72 + kseg * 16 + 8];
      float s = 0.f;
#pragma unroll
      for (int j = 0; j < 8; ++j) s += (float)k0[j] + (float)k1[j];
      ksum_acc += s;
    }

    // ---- G2: KV += K . V^T ----
#pragma unroll
    for (int ks = 0; ks < 2; ++ks) {
      bf16x8 af[4], bfv[4];
#pragma unroll
      for (int i = 0; i < 4; ++i)
        af[i] = *(const bf16x8*)&Kcp[((4 * ckg + i) * 16 + m) * 72 + ks * 32 + q * 8];
#pragma unroll
      for (int j = 0; j < 4; ++j)
        bfv[j] = *(const bf16x8*)&Vcp[((4 * cvg + j) * 16 + m) * 72 + ks * 32 + q * 8];
#pragma unroll
      for (int i = 0; i < 4; ++i)
#pragma unroll
        for (int j = 0; j < 4; ++j)
          accKV[i][j] = __builtin_amdgcn_mfma_f32_16x16x32_bf16(af[i], bfv[j], accKV[i][j], 0, 0, 0);
    }
  }

  // ---- block epilogue ----
  atomicAdd(&ksum[b * CH + (tid & 255)], ksum_acc);
  if (mode == 0) {
    float* KVp = kvdst + (size_t)blockIdx.x * 65536;
#pragma unroll
    for (int i = 0; i < 4; ++i)
#pragma unroll
      for (int j = 0; j < 4; ++j)
#pragma unroll
        for (int r = 0; r < 4; ++r) {
          const int row = (4 * ckg + i) * 16 + q * 4 + r;
          const int col = (4 * cvg + j) * 16 + m;
          KVp[row * CH + col] = accKV[i][j][r];
        }
  } else {
    float* KVb = kvdst + (size_t)b * 65536;
#pragma unroll
    for (int i = 0; i < 4; ++i)
#pragma unroll
      for (int j = 0; j < 4; ++j)
#pragma unroll
        for (int r = 0; r < 4; ++r) {
          const int row = (4 * ckg + i) * 16 + q * 4 + r;
          const int col = (4 * cvg + j) * 16 + m;
          atomicAdd(&KVb[row * CH + col], accKV[i][j][r]);
        }
  }
}

// ---------------- KV[b] = sum of 32 per-block partials ----------------
// grid 512 x 256: 524288 outputs, 4 per thread
__global__ __launch_bounds__(256) void kv_reduce_kernel(const float* __restrict__ kvpart,
                                                        float* __restrict__ KV) {
  const int base = blockIdx.x * 1024 + threadIdx.x;
#pragma unroll
  for (int i = 0; i < 4; ++i) {
    const int e = base + i * 256;
    const int b = e >> 16;
    const int rc = e & 65535;
    const float* p = kvpart + (size_t)(b * 32) * 65536 + rc;
    float s = 0.f;
#pragma unroll 8
    for (int j = 0; j < 32; ++j) s += p[(size_t)j * 65536];
    KV[e] = s;
  }
}

// ---------------- M[b] = Wp . (KV / (ksum+eps)) -> bf16 ----------------
__global__ __launch_bounds__(256) void m_kernel(const float* __restrict__ Wp,
                                                const float* __restrict__ KV,
                                                const float* __restrict__ ksum,
                                                u16* __restrict__ Mb) {
  __shared__ float WpL[16 * 256];
  const int b = blockIdx.x >> 4;
  const int rt = blockIdx.x & 15;
  const int tid = threadIdx.x;
#pragma unroll
  for (int i = 0; i < 16; ++i) WpL[i * 256 + tid] = Wp[(rt * 16 + i) * 256 + tid];
  __syncthreads();
  float acc[16];
#pragma unroll
  for (int r = 0; r < 16; ++r) acc[r] = 0.f;
  const float* KVb = KV + (size_t)b * 65536;
  const float* ksb = ksum + b * 256;
  for (int k = 0; k < 256; ++k) {
    const float rs = 1.f / (ksb[k] + ATTN_EPS);
    const float v = KVb[k * 256 + tid] * rs;
#pragma unroll
    for (int r = 0; r < 16; ++r) acc[r] += WpL[r * 256 + k] * v;
  }
#pragma unroll
  for (int r = 0; r < 16; ++r) Mb[(size_t)b * 65536 + (rt * 16 + r) * 256 + tid] = f2bf(acc[r]);
}

// ---------------- out = M . (elu(Wq.xn+bq)+1) + bp + x ----------------
// grid 2048: b = bid>>8, 64-pixel chunk = bid&255
// Single 36KB LDS buffer (q aliases xn) -> 4 blocks/CU.
__global__ __launch_bounds__(256, 4) void out_kernel(
    const float* __restrict__ x, const u16* __restrict__ Wqb, const float* __restrict__ bq,
    const float* __restrict__ sA, const float* __restrict__ sB, const u16* __restrict__ Mb,
    const float* __restrict__ bp, float* __restrict__ out) {
  __shared__ __align__(16) u16 buf[64 * 288];  // xn pixel-major, then q pixel-major
  const int b = blockIdx.x >> 8;
  const int pix0 = (blockIdx.x & 255) * 64;
  const int tid = threadIdx.x;
  const int wave = tid >> 6;  // 0..3
  const int lane = tid & 63;
  const int m = lane & 15;
  const int q = lane >> 4;

  const float* xb = x + (size_t)b * CH * NPIX;
  const float* sAb = sA + b * CH;
  const float* sBb = sB + b * CH;

  const int p_ = tid & 63;
  const int cq = tid >> 6;  // 0..3
#pragma unroll
  for (int i = 0; i < 16; ++i) {
    const int c = (cq + 4 * i) * 4;
    const float v0 = xb[(size_t)(c + 0) * NPIX + pix0 + p_] * sAb[c + 0] + sBb[c + 0];
    const float v1 = xb[(size_t)(c + 1) * NPIX + pix0 + p_] * sAb[c + 1] + sBb[c + 1];
    const float v2 = xb[(size_t)(c + 2) * NPIX + pix0 + p_] * sAb[c + 2] + sBb[c + 2];
    const float v3 = xb[(size_t)(c + 3) * NPIX + pix0 + p_] * sAb[c + 3] + sBb[c + 3];
    const unsigned int lo = (unsigned int)f2bf(v0) | ((unsigned int)f2bf(v1) << 16);
    const unsigned int hi = (unsigned int)f2bf(v2) | ((unsigned int)f2bf(v3) << 16);
    *(uint2*)&buf[p_ * 288 + c] = make_uint2(lo, hi);
  }
  __syncthreads();

  // G3: q^T = xn^T . Wq^T  (D rows = pixels, cols = c2)
  f32x4 aq[4][4];  // [pt][ct]
#pragma unroll
  for (int pt = 0; pt < 4; ++pt)
#pragma unroll
    for (int ct = 0; ct < 4; ++ct) aq[pt][ct] = {0.f, 0.f, 0.f, 0.f};
#pragma unroll
  for (int ks = 0; ks < 8; ++ks) {
    bf16x8 af[4];
#pragma unroll
    for (int pt = 0; pt < 4; ++pt)
      af[pt] = *(const bf16x8*)&buf[(pt * 16 + m) * 288 + ks * 32 + q * 8];
#pragma unroll
    for (int ct = 0; ct < 4; ++ct) {
      const bf16x8 bfr = *(const bf16x8*)(Wqb + ((4 * wave + ct) * 16 + m) * 256 + ks * 32 + q * 8);
#pragma unroll
      for (int pt = 0; pt < 4; ++pt)
        aq[pt][ct] = __builtin_amdgcn_mfma_f32_16x16x32_bf16(af[pt], bfr, aq[pt][ct], 0, 0, 0);
    }
  }
  __syncthreads();  // all xn reads done; reuse buf for q
#pragma unroll
  for (int ct = 0; ct < 4; ++ct) {
    const int c2 = (4 * wave + ct) * 16 + m;
    const float bias = bq[c2];
#pragma unroll
    for (int pt = 0; pt < 4; ++pt)
#pragma unroll
      for (int r = 0; r < 4; ++r) {
        float v = aq[pt][ct][r] + bias;
        v = v > 0.f ? v + 1.f : __expf(v);
        buf[(pt * 16 + q * 4 + r) * 288 + c2] = f2bf(v);
      }
  }
  __syncthreads();

  // G4: out = M . q
  f32x4 ao[4][4];  // [ct][pt]
#pragma unroll
  for (int ct = 0; ct < 4; ++ct)
#pragma unroll
    for (int pt = 0; pt < 4; ++pt) ao[ct][pt] = {0.f, 0.f, 0.f, 0.f};
  const u16* Ab = Mb + (size_t)b * 65536;
#pragma unroll
  for (int ks = 0; ks < 8; ++ks) {
    bf16x8 af2[4];
#pragma unroll
    for (int ct = 0; ct < 4; ++ct)
      af2[ct] = *(const bf16x8*)(Ab + ((4 * wave + ct) * 16 + m) * 256 + ks * 32 + q * 8);
#pragma unroll
    for (int pt = 0; pt < 4; ++pt) {
      const bf16x8 bfr = *(const bf16x8*)&buf[(pt * 16 + m) * 288 + ks * 32 + q * 8];
#pragma unroll
      for (int ct = 0; ct < 4; ++ct)
        ao[ct][pt] = __builtin_amdgcn_mfma_f32_16x16x32_bf16(af2[ct], bfr, ao[ct][pt], 0, 0, 0);
    }
  }
  float* ob = out + (size_t)b * CH * NPIX;
#pragma unroll
  for (int ct = 0; ct < 4; ++ct)
#pragma unroll
    for (int r = 0; r < 4; ++r) {
      const int row = (4 * wave + ct) * 16 + q * 4 + r;
      const float bias = bp[row];
#pragma unroll
      for (int pt = 0; pt < 4; ++pt) {
        const int idx = row * NPIX + pix0 + pt * 16 + m;
        ob[idx] = ao[ct][pt][r] + bias + xb[idx];
      }
    }
}

// ---------------- launch ----------------
extern "C" void kernel_launch(void* const* d_in, const int* in_sizes, int n_in,
                              void* d_out, int out_size, void* d_ws, size_t ws_size,
                              hipStream_t stream) {
  const float* x     = (const float*)d_in[0];
  const float* gamma = (const float*)d_in[1];
  const float* beta  = (const float*)d_in[2];
  const float* Wq    = (const float*)d_in[3];
  const float* bq    = (const float*)d_in[4];
  const float* Wk    = (const float*)d_in[5];
  const float* bk    = (const float*)d_in[6];
  const float* Wv    = (const float*)d_in[7];
  const float* bv    = (const float*)d_in[8];
  const float* Wp    = (const float*)d_in[9];
  const float* bp    = (const float*)d_in[10];
  float* out = (float*)d_out;

  float* wsf  = (float*)d_ws;
  float* sum  = wsf;              // 64
  float* sqs  = wsf + 64;         // 64
  float* ksum = wsf + 128;        // 2048
  float* KV   = wsf + 2176;       // 524288
  float* sA   = wsf + 526464;     // 2048
  float* sB   = wsf + 528512;     // 2048
  u16* Wqb = (u16*)(wsf + 530560);  // 65536 u16
  u16* Wkb = Wqb + 65536;
  u16* Wvb = Wkb + 65536;
  u16* Mb  = Wvb + 65536;           // 524288 u16 (layout ends ~3.6 MB)

  // KV partials (256 x 64K floats = 64 MiB) live in d_ws at the 4 MiB mark,
  // ONLY if the workspace is big enough. Never use d_out as mid-pipeline
  // scratch (round-2 lesson: d_out is write-only, final-kernel-only).
  const bool bigws = ws_size >= ((size_t)72 << 20);
  float* kvpart = bigws ? (wsf + ((size_t)1 << 20)) : KV;  // +4 MiB in floats
  const int mode = bigws ? 0 : 1;

  // mode 0: zero sum/sqs/ksum only; mode 1: also zero KV (atomic target).
  hipMemsetAsync(wsf, 0, (size_t)(bigws ? 2176 : 526464) * sizeof(float), stream);
  conv_w_kernel<<<256, 256, 0, stream>>>(Wq, Wk, Wv, Wqb, Wkb, Wvb);
  stats_kernel<<<512, 256, 0, stream>>>(x, sum, sqs);
  finalize_kernel<<<8, 256, 0, stream>>>(sum, sqs, gamma, beta, sA, sB);
  fused_kv_kernel<<<256, 1024, 0, stream>>>(x, Wkb, Wvb, bk, bv, sA, sB, ksum, kvpart, mode);
  if (bigws) kv_reduce_kernel<<<512, 256, 0, stream>>>(kvpart, KV);
  m_kernel<<<128, 256, 0, stream>>>(Wp, KV, ksum, Mb);
  out_kernel<<<2048, 256, 0, stream>>>(x, Wqb, bq, sA, sB, Mb, bp, out);
}